// Round 7
// baseline (1076.139 us; speedup 1.0000x reference)
//
#include <hip/hip_runtime.h>
#include <hip/hip_bf16.h>
#include <math.h>

#define N_NODES 50000
#define N_EDGES 500000
#define SD 128
#define VD 3
#define HID 64
#define DEPTH 4

// edge weights per layer, MFMA-fragment order: frag = [f][lane(64)][8 shorts]
// W1F: 32 frags (f = ks*4+t, ks 0..7 over K=256, t 0..3 over N=64)
// W2F:  8 frags (f = ks*4+t, ks 0..1)
// W3F: 18 frags (f = ks*9+t, ks 0..1, t 0..8 over N=144 padded)
#define NF1 32
#define NF2 8
#define NF3 18
#define W1F_SH (NF1 * 512)
#define W2F_SH (NF2 * 512)
#define W3F_SH (NF3 * 512)
#define WPK_SH (W1F_SH + W2F_SH + W3F_SH)   // 29696 shorts per layer

// node weights per layer: Wn1T (64 x 256) + Wn2T (128 x 64), row-major transposed
#define WN1T_SH (64 * 256)
#define WN2T_SH (128 * 64)
#define WN_SH (WN1T_SH + WN2T_SH)

#define EDGE_GRID 512
#define NTILES (N_EDGES / 16)               // 31250
#define EDGE_ITERS ((NTILES + EDGE_GRID * 4 - 1) / (EDGE_GRID * 4))   // 16

typedef __attribute__((ext_vector_type(8))) short short8;
typedef __attribute__((ext_vector_type(4))) float f32x4;

__device__ __forceinline__ float silu_f(float x) {
    return x / (1.0f + __expf(-x));
}

__device__ __forceinline__ unsigned short f2bf(float x) {
    __hip_bfloat16 h = __float2bfloat16(x);
    return *reinterpret_cast<unsigned short*>(&h);
}

__device__ __forceinline__ float bf2f(unsigned short u) {
    union { unsigned int i; float f; } c; c.i = ((unsigned int)u) << 16;
    return c.f;
}

// 8 consecutive fp32 -> bf16 short8 fragment
__device__ __forceinline__ short8 cvt8(const float* __restrict__ p) {
    short8 o;
    #pragma unroll
    for (int i = 0; i < 8; i++) o[i] = (short)f2bf(p[i]);
    return o;
}

// ---------------- setup kernels ----------------

__global__ void cast_s_kernel(const float* __restrict__ in, float* __restrict__ out,
                              unsigned short* __restrict__ out_bf, int n) {
    int i = blockIdx.x * blockDim.x + threadIdx.x;
    if (i < n) { float x = in[i]; out[i] = x; out_bf[i] = f2bf(x); }
}

__global__ void copy_kernel(const float* __restrict__ in, float* __restrict__ out, int n) {
    int i = blockIdx.x * blockDim.x + threadIdx.x;
    if (i < n) out[i] = in[i];
}

__global__ void prep_edges(const int* __restrict__ ei, const float* __restrict__ d,
                           float* __restrict__ C, int* __restrict__ cnti) {
    int e = blockIdx.x * blockDim.x + threadIdx.x;
    if (e >= N_EDGES) return;
    float de = d[e];
    float c = 0.5f * (cosf(3.14159265358979323846f * de * (1.0f / 5.0f)) + 1.0f);
    C[e] = (de < 5.0f) ? c : 0.0f;
    atomicAdd(&cnti[ei[e]], 1);
}

__global__ void inv_cnt_kernel(const int* __restrict__ cnti, float* __restrict__ inv_cnt) {
    int i = blockIdx.x * blockDim.x + threadIdx.x;
    if (i < N_NODES) inv_cnt[i] = 1.0f / fmaxf((float)cnti[i], 1.0f);
}

// multi-block scan: phase 1 — per-block exclusive scan + block sums
__global__ __launch_bounds__(1024) void scan_block(const int* __restrict__ cnti,
                                                   int* __restrict__ offs,
                                                   int* __restrict__ bsum) {
    __shared__ int sh[1024];
    int tid = threadIdx.x;
    int idx = blockIdx.x * 1024 + tid;
    int x = (idx < N_NODES) ? cnti[idx] : 0;
    sh[tid] = x;
    __syncthreads();
    for (int off = 1; off < 1024; off <<= 1) {
        int y = (tid >= off) ? sh[tid - off] : 0;
        __syncthreads();
        sh[tid] += y;
        __syncthreads();
    }
    if (idx < N_NODES) offs[idx] = sh[tid] - x;   // exclusive, block-local
    if (tid == 1023) bsum[blockIdx.x] = sh[1023];
}

__global__ void scan_partials(int* __restrict__ bsum, int nb, int* __restrict__ offs_total) {
    if (threadIdx.x == 0 && blockIdx.x == 0) {
        int acc = 0;
        for (int i = 0; i < nb; i++) { int t = bsum[i]; bsum[i] = acc; acc += t; }
        offs_total[0] = acc;
    }
}

__global__ __launch_bounds__(1024) void scan_apply(int* __restrict__ offs,
                                                   const int* __restrict__ bsum) {
    int idx = blockIdx.x * 1024 + threadIdx.x;
    if (idx < N_NODES) offs[idx] += bsum[blockIdx.x];
}

__global__ void build_perm(const int* __restrict__ ei, const int* __restrict__ offs,
                           int* __restrict__ cursor, int* __restrict__ eids) {
    int e = blockIdx.x * blockDim.x + threadIdx.x;
    if (e >= N_EDGES) return;
    int dst = ei[e];
    int p = offs[dst] + atomicAdd(&cursor[dst], 1);
    eids[p] = e;
}

// permute per-edge data into CSR (dst-sorted) order
__global__ void permute_edges(const int* __restrict__ ei, const float* __restrict__ d,
                              const float* __restrict__ C, const float* __restrict__ r,
                              const int* __restrict__ eids,
                              int* __restrict__ dst_s, int* __restrict__ src_s,
                              float* __restrict__ d_s, float* __restrict__ C_s,
                              float* __restrict__ r_s) {
    int p = blockIdx.x * blockDim.x + threadIdx.x;
    if (p >= N_EDGES) return;
    int e = eids[p];
    dst_s[p] = ei[e];
    src_s[p] = ei[N_EDGES + e];
    d_s[p] = d[e];
    C_s[p] = C[e];
    r_s[3 * (size_t)p + 0] = r[3 * (size_t)e + 0];
    r_s[3 * (size_t)p + 1] = r[3 * (size_t)e + 1];
    r_s[3 * (size_t)p + 2] = r[3 * (size_t)e + 2];
}

// pack edge-MLP weights into bf16 MFMA-fragment order (see defines above)
__global__ void prep_weights(const float* __restrict__ W1, const float* __restrict__ W2,
                             const float* __restrict__ W3, unsigned short* __restrict__ Wpk) {
    int idx = blockIdx.x * blockDim.x + threadIdx.x;
    if (idx >= DEPTH * WPK_SH) return;
    int l = idx / WPK_SH;
    int j = idx - l * WPK_SH;
    float val = 0.0f;
    if (j < W1F_SH) {
        int f = j >> 9, rrr = j & 511;
        int lane = rrr >> 3, jj = rrr & 7;
        int q = lane >> 4, lo = lane & 15;
        int ks = f >> 2, t = f & 3;
        int k = ks * 32 + q * 8 + jj;        // 0..255
        int n = t * 16 + lo;                 // 0..63
        val = W1[((size_t)l * 257 + k) * 64 + n];
    } else if (j < W1F_SH + W2F_SH) {
        int jj2 = j - W1F_SH;
        int f = jj2 >> 9, rrr = jj2 & 511;
        int lane = rrr >> 3, jj = rrr & 7;
        int q = lane >> 4, lo = lane & 15;
        int ks = f >> 2, t = f & 3;
        int k = ks * 32 + q * 8 + jj;        // 0..63
        int n = t * 16 + lo;
        val = W2[((size_t)l * 64 + k) * 64 + n];
    } else {
        int jj3 = j - W1F_SH - W2F_SH;
        int f = jj3 >> 9, rrr = jj3 & 511;
        int lane = rrr >> 3, jj = rrr & 7;
        int q = lane >> 4, lo = lane & 15;
        int ks = f / 9, t = f - ks * 9;
        int k = ks * 32 + q * 8 + jj;        // 0..63
        int n = t * 16 + lo;                 // 0..143 (valid < 134)
        val = (n < 134) ? W3[((size_t)l * 64 + k) * 134 + n] : 0.0f;
    }
    Wpk[idx] = f2bf(val);
}

// pack transposed bf16 node-MLP weights: Wn1T[n][k] (64x256), Wn2T[n][k] (128x64)
__global__ void prep_node_weights(const float* __restrict__ Wn1, const float* __restrict__ Wn2,
                                  unsigned short* __restrict__ Wnpk) {
    int idx = blockIdx.x * blockDim.x + threadIdx.x;
    if (idx >= DEPTH * WN_SH) return;
    int l = idx / WN_SH;
    int j = idx - l * WN_SH;
    float val;
    if (j < WN1T_SH) {
        int n = j / 256, k = j - n * 256;
        val = Wn1[((size_t)l * 256 + k) * 64 + n];
    } else {
        int jj = j - WN1T_SH;
        int n = jj / 64, k = jj - n * 64;
        val = Wn2[((size_t)l * 64 + k) * 128 + n];
    }
    Wnpk[idx] = f2bf(val);
}

// ---------------- fused persistent MFMA edge kernel ----------------
// 512 blocks x 4 waves; W1F/W3F in LDS (fragment order); depth-1 pipelined
// A-fragment gathers. NEW: aggregation fused — dst-sorted segmented reduction
// within each 16-edge tile, fp32 atomicAdd into dense s_agg / v_agg
// (~2.5 segments/tile, 64B-coalesced atomic rows). smsg/vmsg eliminated.
__global__ __launch_bounds__(256, 2) void edge_mfma(
    const unsigned short* __restrict__ s_bf, const float* __restrict__ v,
    const int* __restrict__ dst_s, const int* __restrict__ src_s,
    const float* __restrict__ d_s, const float* __restrict__ C_s,
    const float* __restrict__ r_s,
    const unsigned short* __restrict__ Wpk_l,
    const float* __restrict__ W1r,              // fp32 W1 row 256 (the d feature)
    const float* __restrict__ b1, const float* __restrict__ b2,
    const float* __restrict__ b3,
    float* __restrict__ s_agg, float* __restrict__ v_agg)
{
    __shared__ __align__(16) unsigned short w1f[W1F_SH];      // 32768 B
    __shared__ __align__(16) unsigned short w3f[W3F_SH];      // 18432 B
    __shared__ __align__(16) unsigned short Hb[4][16 * 72];   //  9216 B
    __shared__ float gb[4][16][6];                            //  1536 B
    __shared__ float vtile[4][16][9];                         //  2304 B
    __shared__ int tdst[4][16];                               //   256 B

    const int tid  = threadIdx.x;
    const int wl   = tid >> 6;
    const int lane = tid & 63;
    const int lo   = lane & 15;
    const int q    = lane >> 4;

    // ---- stage W1F + W3F into LDS (fragment order = straight 16B copies) ----
    {
        const short8* g1 = reinterpret_cast<const short8*>(Wpk_l);
        const short8* g3 = reinterpret_cast<const short8*>(Wpk_l + W1F_SH + W2F_SH);
        short8* l1 = reinterpret_cast<short8*>(w1f);
        short8* l3 = reinterpret_cast<short8*>(w3f);
        for (int i = tid; i < W1F_SH / 8; i += 256) l1[i] = g1[i];
        for (int i = tid; i < W3F_SH / 8; i += 256) l3[i] = g3[i];
    }
    __syncthreads();

    const unsigned short* w2g = Wpk_l + W1F_SH;

    float bb1[4], wr1[4], bb2[4], bb3[9];
    #pragma unroll
    for (int t = 0; t < 4; t++) { bb1[t] = b1[t * 16 + lo]; wr1[t] = W1r[t * 16 + lo]; }
    #pragma unroll
    for (int t = 0; t < 4; t++) bb2[t] = b2[t * 16 + lo];
    #pragma unroll
    for (int t = 0; t < 9; t++) { int n = t * 16 + lo; bb3[t] = (n < 134) ? b3[n] : 0.0f; }

    // ---- pipeline state: current tile ----
    int raw0 = blockIdx.x * 4 + wl;          // it=0: always < NTILES
    bool val_c = true;
    long eb = (long)raw0 * 16;
    int dn_c;
    short8 ad[4], asf[4];
    float4 dd4, ce4;
    float vsr[9], rv[3], cel_t = 0.0f;
    {
        dn_c = dst_s[eb + lo];
        int sn = src_s[eb + lo];
        dd4 = *reinterpret_cast<const float4*>(d_s + eb + 4 * q);
        ce4 = *reinterpret_cast<const float4*>(C_s + eb + 4 * q);
        const unsigned short* rd = s_bf + (size_t)dn_c * SD;
        const unsigned short* rs = s_bf + (size_t)sn * SD;
        #pragma unroll
        for (int ks = 0; ks < 4; ks++) {
            ad[ks]  = *reinterpret_cast<const short8*>(rd + ks * 32 + q * 8);
            asf[ks] = *reinterpret_cast<const short8*>(rs + ks * 32 + q * 8);
        }
        if (lane < 16) {
            cel_t = C_s[eb + lane];
            #pragma unroll
            for (int t = 0; t < 9; t++) vsr[t] = v[(size_t)sn * 9 + t];
            #pragma unroll
            for (int t = 0; t < 3; t++) rv[t] = r_s[3 * eb + 3 * lane + t];
        }
    }

    for (int it = 0; it < EDGE_ITERS; it++) {
        // ---- phase A: next tile's index loads ----
        int raw_n = (it + 1) * (EDGE_GRID * 4) + blockIdx.x * 4 + wl;
        bool val_n = (raw_n < NTILES);
        int tile_n = val_n ? raw_n : (NTILES - 1);
        long ebn = (long)tile_n * 16;
        int dn_n = dst_s[ebn + lo];
        int sn_n = src_s[ebn + lo];
        float4 dd4_n = *reinterpret_cast<const float4*>(d_s + ebn + 4 * q);
        float4 ce4_n = *reinterpret_cast<const float4*>(C_s + ebn + 4 * q);
        float cel_n = 0.0f, rv_n[3];
        if (lane < 16) {
            cel_n = C_s[ebn + lane];
            #pragma unroll
            for (int t = 0; t < 3; t++) rv_n[t] = r_s[3 * ebn + 3 * lane + t];
        }

        // ---- L1: [s_dst | s_src | d] @ W1 + b1 (K=256) ----
        f32x4 acc1[4];
        #pragma unroll
        for (int t = 0; t < 4; t++) {
            float dd[4] = { dd4.x, dd4.y, dd4.z, dd4.w };
            #pragma unroll
            for (int rr = 0; rr < 4; rr++) acc1[t][rr] = bb1[t] + dd[rr] * wr1[t];
        }
        #pragma unroll
        for (int ks = 0; ks < 4; ks++) {
            #pragma unroll
            for (int t = 0; t < 4; t++) {
                short8 b = *reinterpret_cast<const short8*>(&w1f[((ks * 4 + t) * 64 + lane) * 8]);
                acc1[t] = __builtin_amdgcn_mfma_f32_16x16x32_bf16(ad[ks], b, acc1[t], 0, 0, 0);
            }
        }
        #pragma unroll
        for (int ks = 0; ks < 4; ks++) {
            #pragma unroll
            for (int t = 0; t < 4; t++) {
                short8 b = *reinterpret_cast<const short8*>(&w1f[(((ks + 4) * 4 + t) * 64 + lane) * 8]);
                acc1[t] = __builtin_amdgcn_mfma_f32_16x16x32_bf16(asf[ks], b, acc1[t], 0, 0, 0);
            }
        }
        #pragma unroll
        for (int t = 0; t < 4; t++)
            #pragma unroll
            for (int rr = 0; rr < 4; rr++)
                Hb[wl][(4 * q + rr) * 72 + t * 16 + lo] = f2bf(silu_f(acc1[t][rr]));
        __syncthreads();

        // ---- L2: H1 @ W2 + b2 (K=64), W2 frags from global (L1-hot) ----
        short8 a2[2];
        #pragma unroll
        for (int ks = 0; ks < 2; ks++)
            a2[ks] = *reinterpret_cast<const short8*>(&Hb[wl][lo * 72 + ks * 32 + q * 8]);
        f32x4 acc2[4];
        #pragma unroll
        for (int t = 0; t < 4; t++) {
            #pragma unroll
            for (int rr = 0; rr < 4; rr++) acc2[t][rr] = bb2[t];
        }
        #pragma unroll
        for (int ks = 0; ks < 2; ks++) {
            #pragma unroll
            for (int t = 0; t < 4; t++) {
                short8 b = *reinterpret_cast<const short8*>(w2g + ((ks * 4 + t) * 64 + lane) * 8);
                acc2[t] = __builtin_amdgcn_mfma_f32_16x16x32_bf16(a2[ks], b, acc2[t], 0, 0, 0);
            }
        }

        // ---- phase B: next tile's A-fragment + tail gathers ----
        short8 ad_n[4], as_n[4];
        {
            const unsigned short* rd = s_bf + (size_t)dn_n * SD;
            const unsigned short* rs = s_bf + (size_t)sn_n * SD;
            #pragma unroll
            for (int ks = 0; ks < 4; ks++) {
                ad_n[ks] = *reinterpret_cast<const short8*>(rd + ks * 32 + q * 8);
                as_n[ks] = *reinterpret_cast<const short8*>(rs + ks * 32 + q * 8);
            }
        }
        float vsr_n[9];
        if (lane < 16) {
            #pragma unroll
            for (int t = 0; t < 9; t++) vsr_n[t] = v[(size_t)sn_n * 9 + t];
        }

        __syncthreads();
        #pragma unroll
        for (int t = 0; t < 4; t++)
            #pragma unroll
            for (int rr = 0; rr < 4; rr++)
                Hb[wl][(4 * q + rr) * 72 + t * 16 + lo] = f2bf(silu_f(acc2[t][rr]));
        __syncthreads();

        // ---- L3: H2 @ W3 + b3 (K=64, 144 padded cols), W3 frags from LDS ----
        short8 a3[2];
        #pragma unroll
        for (int ks = 0; ks < 2; ks++)
            a3[ks] = *reinterpret_cast<const short8*>(&Hb[wl][lo * 72 + ks * 32 + q * 8]);
        f32x4 acc3[9];
        #pragma unroll
        for (int t = 0; t < 9; t++) {
            #pragma unroll
            for (int rr = 0; rr < 4; rr++) acc3[t][rr] = bb3[t];
        }
        #pragma unroll
        for (int ks = 0; ks < 2; ks++) {
            #pragma unroll
            for (int t = 0; t < 9; t++) {
                short8 b = *reinterpret_cast<const short8*>(&w3f[((ks * 9 + t) * 64 + lane) * 8]);
                acc3[t] = __builtin_amdgcn_mfma_f32_16x16x32_bf16(a3[ks], b, acc3[t], 0, 0, 0);
            }
        }

        // ---- stash gv/gr + tile dst list ----
        if (lo < 6) {
            #pragma unroll
            for (int rr = 0; rr < 4; rr++) gb[wl][4 * q + rr][lo] = acc3[8][rr];
        }
        if (lane < 16) tdst[wl][lane] = dn_c;
        __syncthreads();

        // ---- per-edge v-message into LDS (lanes 0..15) ----
        if (lane < 16) {
            #pragma unroll
            for (int vi = 0; vi < VD; vi++) {
                float gv = gb[wl][lane][vi], gr = gb[wl][lane][VD + vi];
                vtile[wl][lane][vi * 3 + 0] = (vsr[vi * 3 + 0] * gv + rv[0] * gr) * cel_t;
                vtile[wl][lane][vi * 3 + 1] = (vsr[vi * 3 + 1] * gv + rv[1] * gr) * cel_t;
                vtile[wl][lane][vi * 3 + 2] = (vsr[vi * 3 + 2] * gv + rv[2] * gr) * cel_t;
            }
        }
        __syncthreads();

        // ---- fused segmented aggregation (dst-sorted within tile) ----
        if (val_c) {
            float ce[4] = { ce4.x, ce4.y, ce4.z, ce4.w };
            int sseg = 0;
            while (sseg < 16) {
                int dnode = tdst[wl][sseg];
                int eseg = sseg + 1;
                while (eseg < 16 && tdst[wl][eseg] == dnode) eseg++;
                float* srow = s_agg + (size_t)dnode * SD;
                #pragma unroll
                for (int t = 0; t < 8; t++) {
                    float p = 0.0f;
                    #pragma unroll
                    for (int rr = 0; rr < 4; rr++) {
                        int row = 4 * q + rr;
                        p += (row >= sseg && row < eseg) ? acc3[t][rr] * ce[rr] : 0.0f;
                    }
                    p += __shfl_xor(p, 16);
                    p += __shfl_xor(p, 32);
                    if (q == 0) atomicAdd(&srow[t * 16 + lo], p);
                }
                if (lane < 9) {
                    float pv = 0.0f;
                    for (int i = sseg; i < eseg; i++) pv += vtile[wl][i][lane];
                    atomicAdd(&v_agg[(size_t)dnode * 9 + lane], pv);
                }
                sseg = eseg;
            }
        }

        // ---- rotate pipeline state ----
        val_c = val_n;
        eb = ebn;
        dn_c = dn_n;
        dd4 = dd4_n; ce4 = ce4_n;
        cel_t = cel_n;
        #pragma unroll
        for (int ks = 0; ks < 4; ks++) { ad[ks] = ad_n[ks]; asf[ks] = as_n[ks]; }
        #pragma unroll
        for (int t = 0; t < 9; t++) vsr[t] = vsr_n[t];
        #pragma unroll
        for (int t = 0; t < 3; t++) rv[t] = rv_n[t];
    }
}

// ---------------- MFMA node kernel (s_agg now fp32, cvt in-register) ----------------
__global__ __launch_bounds__(256) void node_mfma(
    float* __restrict__ s, float* __restrict__ v, unsigned short* __restrict__ s_bf,
    const float* __restrict__ s_agg, const float* __restrict__ v_agg,
    const float* __restrict__ inv_cnt,
    const unsigned short* __restrict__ Wn_l,
    const float* __restrict__ bn1, const float* __restrict__ bn2)
{
    __shared__ __align__(16) unsigned short Hb[4][16 * 72];   // 9216 B

    const int tid  = threadIdx.x;
    const int wl   = tid >> 6;
    const int lane = tid & 63;
    const int lo   = lane & 15;
    const int q    = lane >> 4;
    const int nb   = blockIdx.x * 64 + wl * 16;   // wave's first node

    int na = nb + lo; if (na > N_NODES - 1) na = N_NODES - 1;
    const unsigned short* rs = s_bf  + (size_t)na * SD;
    const float*          ra = s_agg + (size_t)na * SD;

    // ---- L1: [s | s_agg] @ Wn1 + bn1 ----
    f32x4 acc1[4];
    #pragma unroll
    for (int t = 0; t < 4; t++) {
        float bb = bn1[t * 16 + lo];
        #pragma unroll
        for (int rr = 0; rr < 4; rr++) acc1[t][rr] = bb;
    }
    #pragma unroll
    for (int ks = 0; ks < 4; ks++) {
        short8 a = *reinterpret_cast<const short8*>(rs + ks * 32 + q * 8);
        #pragma unroll
        for (int t = 0; t < 4; t++) {
            short8 b = *reinterpret_cast<const short8*>(Wn_l + (t * 16 + lo) * 256 + ks * 32 + q * 8);
            acc1[t] = __builtin_amdgcn_mfma_f32_16x16x32_bf16(a, b, acc1[t], 0, 0, 0);
        }
    }
    #pragma unroll
    for (int ks = 0; ks < 4; ks++) {
        short8 a = cvt8(ra + ks * 32 + q * 8);
        #pragma unroll
        for (int t = 0; t < 4; t++) {
            short8 b = *reinterpret_cast<const short8*>(Wn_l + (t * 16 + lo) * 256 + 128 + ks * 32 + q * 8);
            acc1[t] = __builtin_amdgcn_mfma_f32_16x16x32_bf16(a, b, acc1[t], 0, 0, 0);
        }
    }
    #pragma unroll
    for (int t = 0; t < 4; t++)
        #pragma unroll
        for (int rr = 0; rr < 4; rr++)
            Hb[wl][(4 * q + rr) * 72 + t * 16 + lo] = f2bf(silu_f(acc1[t][rr]));
    __syncthreads();

    // ---- L2: u @ Wn2 + bn2, K=64, 128 cols ----
    const unsigned short* w2g = Wn_l + WN1T_SH;
    f32x4 acc2[8];
    #pragma unroll
    for (int t = 0; t < 8; t++) {
        float bb = bn2[t * 16 + lo];
        #pragma unroll
        for (int rr = 0; rr < 4; rr++) acc2[t][rr] = bb;
    }
    #pragma unroll
    for (int ks = 0; ks < 2; ks++) {
        short8 a = *reinterpret_cast<const short8*>(&Hb[wl][lo * 72 + ks * 32 + q * 8]);
        #pragma unroll
        for (int t = 0; t < 8; t++) {
            short8 b = *reinterpret_cast<const short8*>(w2g + (t * 16 + lo) * 64 + ks * 32 + q * 8);
            acc2[t] = __builtin_amdgcn_mfma_f32_16x16x32_bf16(a, b, acc2[t], 0, 0, 0);
        }
    }

    // ---- residual add + store fp32 s and bf16 s_bf ----
    #pragma unroll
    for (int t = 0; t < 8; t++) {
        int col = t * 16 + lo;
        #pragma unroll
        for (int rr = 0; rr < 4; rr++) {
            int node = nb + 4 * q + rr;
            if (node < N_NODES) {
                size_t idx = (size_t)node * SD + col;
                float ns = s[idx] + acc2[t][rr];
                s[idx] = ns;
                s_bf[idx] = f2bf(ns);
            }
        }
    }

    // ---- v update: one node per lane (lanes 0..15) ----
    if (lane < 16) {
        int node = nb + lane;
        if (node < N_NODES) {
            float ic = inv_cnt[node];
            #pragma unroll
            for (int t = 0; t < VD * 3; t++)
                v[(size_t)node * 9 + t] += v_agg[(size_t)node * 9 + t] * ic;
        }
    }
}

// ---------------- launch ----------------
extern "C" void kernel_launch(void* const* d_in, const int* in_sizes, int n_in,
                              void* d_out, int out_size, void* d_ws, size_t ws_size,
                              hipStream_t stream)
{
    (void)in_sizes; (void)n_in; (void)out_size; (void)ws_size;
    const float* s_in = (const float*)d_in[0];
    const float* v_in = (const float*)d_in[1];
    const int*   ei   = (const int*)d_in[2];
    const float* d_e  = (const float*)d_in[3];
    const float* r_e  = (const float*)d_in[4];
    const float* W1   = (const float*)d_in[5];
    const float* b1   = (const float*)d_in[6];
    const float* W2   = (const float*)d_in[7];
    const float* b2   = (const float*)d_in[8];
    const float* W3   = (const float*)d_in[9];
    const float* b3   = (const float*)d_in[10];
    const float* Wn1  = (const float*)d_in[11];
    const float* bn1  = (const float*)d_in[12];
    const float* Wn2  = (const float*)d_in[13];
    const float* bn2  = (const float*)d_in[14];

    float* s = (float*)d_out;                 // N*SD, updated in place
    float* v = s + (size_t)N_NODES * SD;      // N*VD*3

    // ---- workspace layout ----
    float* ws      = (float*)d_ws;
    float* s_agg   = ws;                                        // N*SD   (fp32, atomic)
    float* v_agg   = s_agg + (size_t)N_NODES * SD;              // N*9    (contiguous for memset)
    float* cntinv  = v_agg + (size_t)N_NODES * 9;               // N
    float* Cbuf    = cntinv + N_NODES;                          // E
    int*   cnti    = (int*)(Cbuf + N_EDGES);                    // N
    int*   offs    = cnti + N_NODES;                            // N+1
    int*   cursor  = offs + N_NODES + 1;                        // N
    int*   eids    = cursor + N_NODES;                          // E
    int*   bsum    = eids + N_EDGES;                            // 64
    int*   dst_s   = bsum + 64;                                 // E
    int*   src_s   = dst_s + N_EDGES;                           // E
    float* d_s     = (float*)(src_s + N_EDGES);                 // E
    float* C_s     = d_s + N_EDGES;                             // E
    float* r_s     = C_s + N_EDGES;                             // 3E
    uintptr_t up   = (uintptr_t)(r_s + (size_t)3 * N_EDGES);
    up = (up + 15) & ~(uintptr_t)15;
    unsigned short* s_bf = (unsigned short*)up;                 // N*SD
    unsigned short* Wpk  = s_bf + (size_t)N_NODES * SD;         // DEPTH*WPK_SH
    unsigned short* Wnpk = Wpk + (size_t)DEPTH * WPK_SH;        // DEPTH*WN_SH

    hipMemsetAsync(cnti, 0, sizeof(int) * (size_t)N_NODES, stream);
    hipMemsetAsync(cursor, 0, sizeof(int) * (size_t)N_NODES, stream);

    cast_s_kernel<<<(N_NODES * SD + 255) / 256, 256, 0, stream>>>(s_in, s, s_bf, N_NODES * SD);
    copy_kernel<<<(N_NODES * VD * 3 + 255) / 256, 256, 0, stream>>>(v_in, v, N_NODES * VD * 3);
    prep_edges<<<(N_EDGES + 255) / 256, 256, 0, stream>>>(ei, d_e, Cbuf, cnti);
    inv_cnt_kernel<<<(N_NODES + 255) / 256, 256, 0, stream>>>(cnti, cntinv);

    const int NB = (N_NODES + 1023) / 1024;   // 49
    scan_block<<<NB, 1024, 0, stream>>>(cnti, offs, bsum);
    scan_partials<<<1, 64, 0, stream>>>(bsum, NB, offs + N_NODES);
    scan_apply<<<NB, 1024, 0, stream>>>(offs, bsum);
    build_perm<<<(N_EDGES + 255) / 256, 256, 0, stream>>>(ei, offs, cursor, eids);
    permute_edges<<<(N_EDGES + 255) / 256, 256, 0, stream>>>(
        ei, d_e, Cbuf, r_e, eids, dst_s, src_s, d_s, C_s, r_s);

    prep_weights<<<(DEPTH * WPK_SH + 255) / 256, 256, 0, stream>>>(W1, W2, W3, Wpk);
    prep_node_weights<<<(DEPTH * WN_SH + 255) / 256, 256, 0, stream>>>(Wn1, Wn2, Wnpk);

    for (int l = 0; l < DEPTH; l++) {
        // zero s_agg + v_agg (contiguous, fp32 atomic accumulators)
        hipMemsetAsync(s_agg, 0, sizeof(float) * (size_t)N_NODES * (SD + 9), stream);
        edge_mfma<<<EDGE_GRID, 256, 0, stream>>>(
            s_bf, v, dst_s, src_s, d_s, C_s, r_s,
            Wpk + (size_t)l * WPK_SH,
            W1 + ((size_t)l * 257 + 256) * 64,
            b1 + (size_t)l * HID, b2 + (size_t)l * HID, b3 + (size_t)l * (SD + 2 * VD),
            s_agg, v_agg);
        node_mfma<<<(N_NODES + 63) / 64, 256, 0, stream>>>(
            s, v, s_bf, s_agg, v_agg, cntinv,
            Wnpk + (size_t)l * WN_SH,
            bn1 + (size_t)l * HID, bn2 + (size_t)l * SD);
    }
}

// Round 8
// 1007.429 us; speedup vs baseline: 1.0682x; 1.0682x over previous
//
#include <hip/hip_runtime.h>
#include <hip/hip_bf16.h>
#include <math.h>

#define N_NODES 50000
#define N_EDGES 500000
#define SD 128
#define VD 3
#define HID 64
#define DEPTH 4

// edge weights per layer, MFMA-fragment order: frag = [f][lane(64)][8 shorts]
#define NF1 32
#define NF2 8
#define NF3 18
#define W1F_SH (NF1 * 512)
#define W2F_SH (NF2 * 512)
#define W3F_SH (NF3 * 512)
#define WPK_SH (W1F_SH + W2F_SH + W3F_SH)   // 29696 shorts per layer

// node weights per layer: Wn1T (64 x 256) + Wn2T (128 x 64)
#define WN1T_SH (64 * 256)
#define WN2T_SH (128 * 64)
#define WN_SH (WN1T_SH + WN2T_SH)

#define EDGE_GRID 512
#define NTILES (N_EDGES / 16)               // 31250
#define EDGE_ITERS ((NTILES + EDGE_GRID * 4 - 1) / (EDGE_GRID * 4))   // 16

typedef __attribute__((ext_vector_type(8))) short short8;
typedef __attribute__((ext_vector_type(4))) float f32x4;

__device__ __forceinline__ float silu_f(float x) {
    return x / (1.0f + __expf(-x));
}

__device__ __forceinline__ unsigned short f2bf(float x) {
    __hip_bfloat16 h = __float2bfloat16(x);
    return *reinterpret_cast<unsigned short*>(&h);
}

__device__ __forceinline__ float bf2f(unsigned short u) {
    union { unsigned int i; float f; } c; c.i = ((unsigned int)u) << 16;
    return c.f;
}

// 8 consecutive fp32 -> bf16 short8 fragment
__device__ __forceinline__ short8 cvt8(const float* __restrict__ p) {
    short8 o;
    #pragma unroll
    for (int i = 0; i < 8; i++) o[i] = (short)f2bf(p[i]);
    return o;
}

// wave-private LDS fence: per-wave DS ops are in-order on CDNA; this only
// stops the compiler from reordering across it. Zero hardware cost.
__device__ __forceinline__ void wavefence() { __builtin_amdgcn_wave_barrier(); }

// ---------------- setup kernels ----------------

__global__ void cast_s_kernel(const float* __restrict__ in, float* __restrict__ out,
                              unsigned short* __restrict__ out_bf, int n) {
    int i = blockIdx.x * blockDim.x + threadIdx.x;
    if (i < n) { float x = in[i]; out[i] = x; out_bf[i] = f2bf(x); }
}

__global__ void copy_kernel(const float* __restrict__ in, float* __restrict__ out, int n) {
    int i = blockIdx.x * blockDim.x + threadIdx.x;
    if (i < n) out[i] = in[i];
}

__global__ void prep_edges(const int* __restrict__ ei, const float* __restrict__ d,
                           float* __restrict__ C, int* __restrict__ cnti) {
    int e = blockIdx.x * blockDim.x + threadIdx.x;
    if (e >= N_EDGES) return;
    float de = d[e];
    float c = 0.5f * (cosf(3.14159265358979323846f * de * (1.0f / 5.0f)) + 1.0f);
    C[e] = (de < 5.0f) ? c : 0.0f;
    atomicAdd(&cnti[ei[e]], 1);
}

__global__ void inv_cnt_kernel(const int* __restrict__ cnti, float* __restrict__ inv_cnt) {
    int i = blockIdx.x * blockDim.x + threadIdx.x;
    if (i < N_NODES) inv_cnt[i] = 1.0f / fmaxf((float)cnti[i], 1.0f);
}

// multi-block scan: phase 1 — per-block exclusive scan + block sums
__global__ __launch_bounds__(1024) void scan_block(const int* __restrict__ cnti,
                                                   int* __restrict__ offs,
                                                   int* __restrict__ bsum) {
    __shared__ int sh[1024];
    int tid = threadIdx.x;
    int idx = blockIdx.x * 1024 + tid;
    int x = (idx < N_NODES) ? cnti[idx] : 0;
    sh[tid] = x;
    __syncthreads();
    for (int off = 1; off < 1024; off <<= 1) {
        int y = (tid >= off) ? sh[tid - off] : 0;
        __syncthreads();
        sh[tid] += y;
        __syncthreads();
    }
    if (idx < N_NODES) offs[idx] = sh[tid] - x;   // exclusive, block-local
    if (tid == 1023) bsum[blockIdx.x] = sh[1023];
}

__global__ void scan_partials(int* __restrict__ bsum, int nb, int* __restrict__ offs_total) {
    if (threadIdx.x == 0 && blockIdx.x == 0) {
        int acc = 0;
        for (int i = 0; i < nb; i++) { int t = bsum[i]; bsum[i] = acc; acc += t; }
        offs_total[0] = acc;
    }
}

__global__ __launch_bounds__(1024) void scan_apply(int* __restrict__ offs,
                                                   const int* __restrict__ bsum) {
    int idx = blockIdx.x * 1024 + threadIdx.x;
    if (idx < N_NODES) offs[idx] += bsum[blockIdx.x];
}

__global__ void build_perm(const int* __restrict__ ei, const int* __restrict__ offs,
                           int* __restrict__ cursor, int* __restrict__ eids) {
    int e = blockIdx.x * blockDim.x + threadIdx.x;
    if (e >= N_EDGES) return;
    int dst = ei[e];
    int p = offs[dst] + atomicAdd(&cursor[dst], 1);
    eids[p] = e;
}

// permute per-edge data into CSR (dst-sorted) order
__global__ void permute_edges(const int* __restrict__ ei, const float* __restrict__ d,
                              const float* __restrict__ C, const float* __restrict__ r,
                              const int* __restrict__ eids,
                              int* __restrict__ dst_s, int* __restrict__ src_s,
                              float* __restrict__ d_s, float* __restrict__ C_s,
                              float* __restrict__ r_s) {
    int p = blockIdx.x * blockDim.x + threadIdx.x;
    if (p >= N_EDGES) return;
    int e = eids[p];
    dst_s[p] = ei[e];
    src_s[p] = ei[N_EDGES + e];
    d_s[p] = d[e];
    C_s[p] = C[e];
    r_s[3 * (size_t)p + 0] = r[3 * (size_t)e + 0];
    r_s[3 * (size_t)p + 1] = r[3 * (size_t)e + 1];
    r_s[3 * (size_t)p + 2] = r[3 * (size_t)e + 2];
}

// pack edge-MLP weights into bf16 MFMA-fragment order
__global__ void prep_weights(const float* __restrict__ W1, const float* __restrict__ W2,
                             const float* __restrict__ W3, unsigned short* __restrict__ Wpk) {
    int idx = blockIdx.x * blockDim.x + threadIdx.x;
    if (idx >= DEPTH * WPK_SH) return;
    int l = idx / WPK_SH;
    int j = idx - l * WPK_SH;
    float val = 0.0f;
    if (j < W1F_SH) {
        int f = j >> 9, rrr = j & 511;
        int lane = rrr >> 3, jj = rrr & 7;
        int q = lane >> 4, lo = lane & 15;
        int ks = f >> 2, t = f & 3;
        int k = ks * 32 + q * 8 + jj;        // 0..255
        int n = t * 16 + lo;                 // 0..63
        val = W1[((size_t)l * 257 + k) * 64 + n];
    } else if (j < W1F_SH + W2F_SH) {
        int jj2 = j - W1F_SH;
        int f = jj2 >> 9, rrr = jj2 & 511;
        int lane = rrr >> 3, jj = rrr & 7;
        int q = lane >> 4, lo = lane & 15;
        int ks = f >> 2, t = f & 3;
        int k = ks * 32 + q * 8 + jj;        // 0..63
        int n = t * 16 + lo;
        val = W2[((size_t)l * 64 + k) * 64 + n];
    } else {
        int jj3 = j - W1F_SH - W2F_SH;
        int f = jj3 >> 9, rrr = jj3 & 511;
        int lane = rrr >> 3, jj = rrr & 7;
        int q = lane >> 4, lo = lane & 15;
        int ks = f / 9, t = f - ks * 9;
        int k = ks * 32 + q * 8 + jj;        // 0..63
        int n = t * 16 + lo;                 // 0..143 (valid < 134)
        val = (n < 134) ? W3[((size_t)l * 64 + k) * 134 + n] : 0.0f;
    }
    Wpk[idx] = f2bf(val);
}

// pack transposed bf16 node-MLP weights: Wn1T[n][k] (64x256), Wn2T[n][k] (128x64)
__global__ void prep_node_weights(const float* __restrict__ Wn1, const float* __restrict__ Wn2,
                                  unsigned short* __restrict__ Wnpk) {
    int idx = blockIdx.x * blockDim.x + threadIdx.x;
    if (idx >= DEPTH * WN_SH) return;
    int l = idx / WN_SH;
    int j = idx - l * WN_SH;
    float val;
    if (j < WN1T_SH) {
        int n = j / 256, k = j - n * 256;
        val = Wn1[((size_t)l * 256 + k) * 64 + n];
    } else {
        int jj = j - WN1T_SH;
        int n = jj / 64, k = jj - n * 64;
        val = Wn2[((size_t)l * 64 + k) * 128 + n];
    }
    Wnpk[idx] = f2bf(val);
}

// ---------------- fused persistent MFMA edge kernel ----------------
// 512 blocks x 4 waves; W1F/W3F in LDS; depth-1 pipelined A-gathers; fused
// dst-sorted segmented reduction with fp32 atomics. All in-loop LDS buffers
// are wave-private -> NO block barriers in the loop (they were draining
// vmcnt(0): killed both the prefetch pipeline and atomic overlap in r7).
__global__ __launch_bounds__(256, 2) void edge_mfma(
    const unsigned short* __restrict__ s_bf, const float* __restrict__ v,
    const int* __restrict__ dst_s, const int* __restrict__ src_s,
    const float* __restrict__ d_s, const float* __restrict__ C_s,
    const float* __restrict__ r_s,
    const unsigned short* __restrict__ Wpk_l,
    const float* __restrict__ W1r,              // fp32 W1 row 256 (the d feature)
    const float* __restrict__ b1, const float* __restrict__ b2,
    const float* __restrict__ b3,
    float* __restrict__ s_agg, float* __restrict__ v_agg)
{
    __shared__ __align__(16) unsigned short w1f[W1F_SH];      // 32768 B (block-shared, RO)
    __shared__ __align__(16) unsigned short w3f[W3F_SH];      // 18432 B (block-shared, RO)
    __shared__ __align__(16) unsigned short Hb[4][16 * 72];   // wave-private
    __shared__ float gb[4][16][6];                            // wave-private
    __shared__ float vtile[4][16][9];                         // wave-private
    __shared__ int tdst[4][16];                               // wave-private

    const int tid  = threadIdx.x;
    const int wl   = tid >> 6;
    const int lane = tid & 63;
    const int lo   = lane & 15;
    const int q    = lane >> 4;

    // ---- stage W1F + W3F into LDS (fragment order = straight 16B copies) ----
    {
        const short8* g1 = reinterpret_cast<const short8*>(Wpk_l);
        const short8* g3 = reinterpret_cast<const short8*>(Wpk_l + W1F_SH + W2F_SH);
        short8* l1 = reinterpret_cast<short8*>(w1f);
        short8* l3 = reinterpret_cast<short8*>(w3f);
        for (int i = tid; i < W1F_SH / 8; i += 256) l1[i] = g1[i];
        for (int i = tid; i < W3F_SH / 8; i += 256) l3[i] = g3[i];
    }
    __syncthreads();   // the ONLY block barrier: weights visible to all 4 waves

    const unsigned short* w2g = Wpk_l + W1F_SH;

    float bb1[4], wr1[4], bb2[4], bb3[9];
    #pragma unroll
    for (int t = 0; t < 4; t++) { bb1[t] = b1[t * 16 + lo]; wr1[t] = W1r[t * 16 + lo]; }
    #pragma unroll
    for (int t = 0; t < 4; t++) bb2[t] = b2[t * 16 + lo];
    #pragma unroll
    for (int t = 0; t < 9; t++) { int n = t * 16 + lo; bb3[t] = (n < 134) ? b3[n] : 0.0f; }

    // ---- pipeline state: current tile ----
    int raw0 = blockIdx.x * 4 + wl;          // it=0: always < NTILES
    bool val_c = true;
    long eb = (long)raw0 * 16;
    int dn_c;
    short8 ad[4], asf[4];
    float4 dd4, ce4;
    float vsr[9], rv[3], cel_t = 0.0f;
    {
        dn_c = dst_s[eb + lo];
        int sn = src_s[eb + lo];
        dd4 = *reinterpret_cast<const float4*>(d_s + eb + 4 * q);
        ce4 = *reinterpret_cast<const float4*>(C_s + eb + 4 * q);
        const unsigned short* rd = s_bf + (size_t)dn_c * SD;
        const unsigned short* rs = s_bf + (size_t)sn * SD;
        #pragma unroll
        for (int ks = 0; ks < 4; ks++) {
            ad[ks]  = *reinterpret_cast<const short8*>(rd + ks * 32 + q * 8);
            asf[ks] = *reinterpret_cast<const short8*>(rs + ks * 32 + q * 8);
        }
        if (lane < 16) {
            cel_t = C_s[eb + lane];
            #pragma unroll
            for (int t = 0; t < 9; t++) vsr[t] = v[(size_t)sn * 9 + t];
            #pragma unroll
            for (int t = 0; t < 3; t++) rv[t] = r_s[3 * eb + 3 * lane + t];
        }
    }

    for (int it = 0; it < EDGE_ITERS; it++) {
        // ---- phase A: next tile's index loads ----
        int raw_n = (it + 1) * (EDGE_GRID * 4) + blockIdx.x * 4 + wl;
        bool val_n = (raw_n < NTILES);
        int tile_n = val_n ? raw_n : (NTILES - 1);
        long ebn = (long)tile_n * 16;
        int dn_n = dst_s[ebn + lo];
        int sn_n = src_s[ebn + lo];
        float4 dd4_n = *reinterpret_cast<const float4*>(d_s + ebn + 4 * q);
        float4 ce4_n = *reinterpret_cast<const float4*>(C_s + ebn + 4 * q);
        float cel_n = 0.0f, rv_n[3];
        if (lane < 16) {
            cel_n = C_s[ebn + lane];
            #pragma unroll
            for (int t = 0; t < 3; t++) rv_n[t] = r_s[3 * ebn + 3 * lane + t];
        }

        // ---- L1: [s_dst | s_src | d] @ W1 + b1 (K=256) ----
        f32x4 acc1[4];
        #pragma unroll
        for (int t = 0; t < 4; t++) {
            float dd[4] = { dd4.x, dd4.y, dd4.z, dd4.w };
            #pragma unroll
            for (int rr = 0; rr < 4; rr++) acc1[t][rr] = bb1[t] + dd[rr] * wr1[t];
        }
        #pragma unroll
        for (int ks = 0; ks < 4; ks++) {
            #pragma unroll
            for (int t = 0; t < 4; t++) {
                short8 b = *reinterpret_cast<const short8*>(&w1f[((ks * 4 + t) * 64 + lane) * 8]);
                acc1[t] = __builtin_amdgcn_mfma_f32_16x16x32_bf16(ad[ks], b, acc1[t], 0, 0, 0);
            }
        }
        #pragma unroll
        for (int ks = 0; ks < 4; ks++) {
            #pragma unroll
            for (int t = 0; t < 4; t++) {
                short8 b = *reinterpret_cast<const short8*>(&w1f[(((ks + 4) * 4 + t) * 64 + lane) * 8]);
                acc1[t] = __builtin_amdgcn_mfma_f32_16x16x32_bf16(asf[ks], b, acc1[t], 0, 0, 0);
            }
        }
        #pragma unroll
        for (int t = 0; t < 4; t++)
            #pragma unroll
            for (int rr = 0; rr < 4; rr++)
                Hb[wl][(4 * q + rr) * 72 + t * 16 + lo] = f2bf(silu_f(acc1[t][rr]));
        wavefence();

        // ---- L2: H1 @ W2 + b2 (K=64), W2 frags from global (L1-hot) ----
        short8 a2[2];
        #pragma unroll
        for (int ks = 0; ks < 2; ks++)
            a2[ks] = *reinterpret_cast<const short8*>(&Hb[wl][lo * 72 + ks * 32 + q * 8]);
        f32x4 acc2[4];
        #pragma unroll
        for (int t = 0; t < 4; t++) {
            #pragma unroll
            for (int rr = 0; rr < 4; rr++) acc2[t][rr] = bb2[t];
        }
        #pragma unroll
        for (int ks = 0; ks < 2; ks++) {
            #pragma unroll
            for (int t = 0; t < 4; t++) {
                short8 b = *reinterpret_cast<const short8*>(w2g + ((ks * 4 + t) * 64 + lane) * 8);
                acc2[t] = __builtin_amdgcn_mfma_f32_16x16x32_bf16(a2[ks], b, acc2[t], 0, 0, 0);
            }
        }

        // ---- phase B: next tile's A-fragment + tail gathers (stay in flight) ----
        short8 ad_n[4], as_n[4];
        {
            const unsigned short* rd = s_bf + (size_t)dn_n * SD;
            const unsigned short* rs = s_bf + (size_t)sn_n * SD;
            #pragma unroll
            for (int ks = 0; ks < 4; ks++) {
                ad_n[ks] = *reinterpret_cast<const short8*>(rd + ks * 32 + q * 8);
                as_n[ks] = *reinterpret_cast<const short8*>(rs + ks * 32 + q * 8);
            }
        }
        float vsr_n[9];
        if (lane < 16) {
            #pragma unroll
            for (int t = 0; t < 9; t++) vsr_n[t] = v[(size_t)sn_n * 9 + t];
        }

        wavefence();
        #pragma unroll
        for (int t = 0; t < 4; t++)
            #pragma unroll
            for (int rr = 0; rr < 4; rr++)
                Hb[wl][(4 * q + rr) * 72 + t * 16 + lo] = f2bf(silu_f(acc2[t][rr]));
        wavefence();

        // ---- L3: H2 @ W3 + b3 (K=64, 144 padded cols), W3 frags from LDS ----
        short8 a3[2];
        #pragma unroll
        for (int ks = 0; ks < 2; ks++)
            a3[ks] = *reinterpret_cast<const short8*>(&Hb[wl][lo * 72 + ks * 32 + q * 8]);
        f32x4 acc3[9];
        #pragma unroll
        for (int t = 0; t < 9; t++) {
            #pragma unroll
            for (int rr = 0; rr < 4; rr++) acc3[t][rr] = bb3[t];
        }
        #pragma unroll
        for (int ks = 0; ks < 2; ks++) {
            #pragma unroll
            for (int t = 0; t < 9; t++) {
                short8 b = *reinterpret_cast<const short8*>(&w3f[((ks * 9 + t) * 64 + lane) * 8]);
                acc3[t] = __builtin_amdgcn_mfma_f32_16x16x32_bf16(a3[ks], b, acc3[t], 0, 0, 0);
            }
        }

        // ---- stash gv/gr + tile dst list (wave-private LDS) ----
        if (lo < 6) {
            #pragma unroll
            for (int rr = 0; rr < 4; rr++) gb[wl][4 * q + rr][lo] = acc3[8][rr];
        }
        if (lane < 16) tdst[wl][lane] = dn_c;
        wavefence();

        // ---- per-edge v-message into LDS (lanes 0..15) ----
        if (lane < 16) {
            #pragma unroll
            for (int vi = 0; vi < VD; vi++) {
                float gv = gb[wl][lane][vi], gr = gb[wl][lane][VD + vi];
                vtile[wl][lane][vi * 3 + 0] = (vsr[vi * 3 + 0] * gv + rv[0] * gr) * cel_t;
                vtile[wl][lane][vi * 3 + 1] = (vsr[vi * 3 + 1] * gv + rv[1] * gr) * cel_t;
                vtile[wl][lane][vi * 3 + 2] = (vsr[vi * 3 + 2] * gv + rv[2] * gr) * cel_t;
            }
        }
        wavefence();

        // ---- fused segmented aggregation (dst-sorted within tile) ----
        if (val_c) {
            float ce[4] = { ce4.x, ce4.y, ce4.z, ce4.w };
            int sseg = 0;
            while (sseg < 16) {
                int dnode = tdst[wl][sseg];
                int eseg = sseg + 1;
                while (eseg < 16 && tdst[wl][eseg] == dnode) eseg++;
                float* srow = s_agg + (size_t)dnode * SD;
                #pragma unroll
                for (int t = 0; t < 8; t++) {
                    float p = 0.0f;
                    #pragma unroll
                    for (int rr = 0; rr < 4; rr++) {
                        int row = 4 * q + rr;
                        p += (row >= sseg && row < eseg) ? acc3[t][rr] * ce[rr] : 0.0f;
                    }
                    p += __shfl_xor(p, 16);
                    p += __shfl_xor(p, 32);
                    if (q == 0) atomicAdd(&srow[t * 16 + lo], p);
                }
                if (lane < 9) {
                    float pv = 0.0f;
                    for (int i = sseg; i < eseg; i++) pv += vtile[wl][i][lane];
                    atomicAdd(&v_agg[(size_t)dnode * 9 + lane], pv);
                }
                sseg = eseg;
            }
        }

        // ---- rotate pipeline state ----
        val_c = val_n;
        eb = ebn;
        dn_c = dn_n;
        dd4 = dd4_n; ce4 = ce4_n;
        cel_t = cel_n;
        #pragma unroll
        for (int ks = 0; ks < 4; ks++) { ad[ks] = ad_n[ks]; asf[ks] = as_n[ks]; }
        #pragma unroll
        for (int t = 0; t < 9; t++) vsr[t] = vsr_n[t];
        #pragma unroll
        for (int t = 0; t < 3; t++) rv[t] = rv_n[t];
    }
}

// ---------------- MFMA node kernel (s_agg fp32, cvt in-register) ----------------
__global__ __launch_bounds__(256) void node_mfma(
    float* __restrict__ s, float* __restrict__ v, unsigned short* __restrict__ s_bf,
    const float* __restrict__ s_agg, const float* __restrict__ v_agg,
    const float* __restrict__ inv_cnt,
    const unsigned short* __restrict__ Wn_l,
    const float* __restrict__ bn1, const float* __restrict__ bn2)
{
    __shared__ __align__(16) unsigned short Hb[4][16 * 72];   // wave-private

    const int tid  = threadIdx.x;
    const int wl   = tid >> 6;
    const int lane = tid & 63;
    const int lo   = lane & 15;
    const int q    = lane >> 4;
    const int nb   = blockIdx.x * 64 + wl * 16;   // wave's first node

    int na = nb + lo; if (na > N_NODES - 1) na = N_NODES - 1;
    const unsigned short* rs = s_bf  + (size_t)na * SD;
    const float*          ra = s_agg + (size_t)na * SD;

    // ---- L1: [s | s_agg] @ Wn1 + bn1 ----
    f32x4 acc1[4];
    #pragma unroll
    for (int t = 0; t < 4; t++) {
        float bb = bn1[t * 16 + lo];
        #pragma unroll
        for (int rr = 0; rr < 4; rr++) acc1[t][rr] = bb;
    }
    #pragma unroll
    for (int ks = 0; ks < 4; ks++) {
        short8 a = *reinterpret_cast<const short8*>(rs + ks * 32 + q * 8);
        #pragma unroll
        for (int t = 0; t < 4; t++) {
            short8 b = *reinterpret_cast<const short8*>(Wn_l + (t * 16 + lo) * 256 + ks * 32 + q * 8);
            acc1[t] = __builtin_amdgcn_mfma_f32_16x16x32_bf16(a, b, acc1[t], 0, 0, 0);
        }
    }
    #pragma unroll
    for (int ks = 0; ks < 4; ks++) {
        short8 a = cvt8(ra + ks * 32 + q * 8);
        #pragma unroll
        for (int t = 0; t < 4; t++) {
            short8 b = *reinterpret_cast<const short8*>(Wn_l + (t * 16 + lo) * 256 + 128 + ks * 32 + q * 8);
            acc1[t] = __builtin_amdgcn_mfma_f32_16x16x32_bf16(a, b, acc1[t], 0, 0, 0);
        }
    }
    #pragma unroll
    for (int t = 0; t < 4; t++)
        #pragma unroll
        for (int rr = 0; rr < 4; rr++)
            Hb[wl][(4 * q + rr) * 72 + t * 16 + lo] = f2bf(silu_f(acc1[t][rr]));
    wavefence();

    // ---- L2: u @ Wn2 + bn2, K=64, 128 cols ----
    const unsigned short* w2g = Wn_l + WN1T_SH;
    f32x4 acc2[8];
    #pragma unroll
    for (int t = 0; t < 8; t++) {
        float bb = bn2[t * 16 + lo];
        #pragma unroll
        for (int rr = 0; rr < 4; rr++) acc2[t][rr] = bb;
    }
    #pragma unroll
    for (int ks = 0; ks < 2; ks++) {
        short8 a = *reinterpret_cast<const short8*>(&Hb[wl][lo * 72 + ks * 32 + q * 8]);
        #pragma unroll
        for (int t = 0; t < 8; t++) {
            short8 b = *reinterpret_cast<const short8*>(w2g + (t * 16 + lo) * 64 + ks * 32 + q * 8);
            acc2[t] = __builtin_amdgcn_mfma_f32_16x16x32_bf16(a, b, acc2[t], 0, 0, 0);
        }
    }

    // ---- residual add + store fp32 s and bf16 s_bf ----
    #pragma unroll
    for (int t = 0; t < 8; t++) {
        int col = t * 16 + lo;
        #pragma unroll
        for (int rr = 0; rr < 4; rr++) {
            int node = nb + 4 * q + rr;
            if (node < N_NODES) {
                size_t idx = (size_t)node * SD + col;
                float ns = s[idx] + acc2[t][rr];
                s[idx] = ns;
                s_bf[idx] = f2bf(ns);
            }
        }
    }

    // ---- v update: one node per lane (lanes 0..15) ----
    if (lane < 16) {
        int node = nb + lane;
        if (node < N_NODES) {
            float ic = inv_cnt[node];
            #pragma unroll
            for (int t = 0; t < VD * 3; t++)
                v[(size_t)node * 9 + t] += v_agg[(size_t)node * 9 + t] * ic;
        }
    }
}

// ---------------- launch ----------------
extern "C" void kernel_launch(void* const* d_in, const int* in_sizes, int n_in,
                              void* d_out, int out_size, void* d_ws, size_t ws_size,
                              hipStream_t stream)
{
    (void)in_sizes; (void)n_in; (void)out_size; (void)ws_size;
    const float* s_in = (const float*)d_in[0];
    const float* v_in = (const float*)d_in[1];
    const int*   ei   = (const int*)d_in[2];
    const float* d_e  = (const float*)d_in[3];
    const float* r_e  = (const float*)d_in[4];
    const float* W1   = (const float*)d_in[5];
    const float* b1   = (const float*)d_in[6];
    const float* W2   = (const float*)d_in[7];
    const float* b2   = (const float*)d_in[8];
    const float* W3   = (const float*)d_in[9];
    const float* b3   = (const float*)d_in[10];
    const float* Wn1  = (const float*)d_in[11];
    const float* bn1  = (const float*)d_in[12];
    const float* Wn2  = (const float*)d_in[13];
    const float* bn2  = (const float*)d_in[14];

    float* s = (float*)d_out;                 // N*SD, updated in place
    float* v = s + (size_t)N_NODES * SD;      // N*VD*3

    // ---- workspace layout ----
    float* ws      = (float*)d_ws;
    float* s_agg   = ws;                                        // N*SD   (fp32, atomic)
    float* v_agg   = s_agg + (size_t)N_NODES * SD;              // N*9
    float* cntinv  = v_agg + (size_t)N_NODES * 9;               // N
    float* Cbuf    = cntinv + N_NODES;                          // E
    int*   cnti    = (int*)(Cbuf + N_EDGES);                    // N
    int*   offs    = cnti + N_NODES;                            // N+1
    int*   cursor  = offs + N_NODES + 1;                        // N
    int*   eids    = cursor + N_NODES;                          // E
    int*   bsum    = eids + N_EDGES;                            // 64
    int*   dst_s   = bsum + 64;                                 // E
    int*   src_s   = dst_s + N_EDGES;                           // E
    float* d_s     = (float*)(src_s + N_EDGES);                 // E
    float* C_s     = d_s + N_EDGES;                             // E
    float* r_s     = C_s + N_EDGES;                             // 3E
    uintptr_t up   = (uintptr_t)(r_s + (size_t)3 * N_EDGES);
    up = (up + 15) & ~(uintptr_t)15;
    unsigned short* s_bf = (unsigned short*)up;                 // N*SD
    unsigned short* Wpk  = s_bf + (size_t)N_NODES * SD;         // DEPTH*WPK_SH
    unsigned short* Wnpk = Wpk + (size_t)DEPTH * WPK_SH;        // DEPTH*WN_SH

    hipMemsetAsync(cnti, 0, sizeof(int) * (size_t)N_NODES, stream);
    hipMemsetAsync(cursor, 0, sizeof(int) * (size_t)N_NODES, stream);

    cast_s_kernel<<<(N_NODES * SD + 255) / 256, 256, 0, stream>>>(s_in, s, s_bf, N_NODES * SD);
    copy_kernel<<<(N_NODES * VD * 3 + 255) / 256, 256, 0, stream>>>(v_in, v, N_NODES * VD * 3);
    prep_edges<<<(N_EDGES + 255) / 256, 256, 0, stream>>>(ei, d_e, Cbuf, cnti);
    inv_cnt_kernel<<<(N_NODES + 255) / 256, 256, 0, stream>>>(cnti, cntinv);

    const int NB = (N_NODES + 1023) / 1024;   // 49
    scan_block<<<NB, 1024, 0, stream>>>(cnti, offs, bsum);
    scan_partials<<<1, 64, 0, stream>>>(bsum, NB, offs + N_NODES);
    scan_apply<<<NB, 1024, 0, stream>>>(offs, bsum);
    build_perm<<<(N_EDGES + 255) / 256, 256, 0, stream>>>(ei, offs, cursor, eids);
    permute_edges<<<(N_EDGES + 255) / 256, 256, 0, stream>>>(
        ei, d_e, Cbuf, r_e, eids, dst_s, src_s, d_s, C_s, r_s);

    prep_weights<<<(DEPTH * WPK_SH + 255) / 256, 256, 0, stream>>>(W1, W2, W3, Wpk);
    prep_node_weights<<<(DEPTH * WN_SH + 255) / 256, 256, 0, stream>>>(Wn1, Wn2, Wnpk);

    for (int l = 0; l < DEPTH; l++) {
        // zero s_agg + v_agg (contiguous, fp32 atomic accumulators)
        hipMemsetAsync(s_agg, 0, sizeof(float) * (size_t)N_NODES * (SD + 9), stream);
        edge_mfma<<<EDGE_GRID, 256, 0, stream>>>(
            s_bf, v, dst_s, src_s, d_s, C_s, r_s,
            Wpk + (size_t)l * WPK_SH,
            W1 + ((size_t)l * 257 + 256) * 64,
            b1 + (size_t)l * HID, b2 + (size_t)l * HID, b3 + (size_t)l * (SD + 2 * VD),
            s_agg, v_agg);
        node_mfma<<<(N_NODES + 63) / 64, 256, 0, stream>>>(
            s, v, s_bf, s_agg, v_agg, cntinv,
            Wnpk + (size_t)l * WN_SH,
            bn1 + (size_t)l * HID, bn2 + (size_t)l * SD);
    }
}